// Round 1
// 863.319 us; speedup vs baseline: 1.0532x; 1.0532x over previous
//
#include <hip/hip_runtime.h>
#include <math.h>

#define NN 50000
#define NE 800000

typedef __attribute__((ext_vector_type(8))) short bf8;   // 8 bf16 = 4 VGPRs (MFMA A/B frag)
typedef __attribute__((ext_vector_type(4))) float f32x4; // MFMA C/D frag
typedef unsigned int u32;

__device__ __forceinline__ unsigned short f2b(float f){
  union{float f;unsigned u;} v; v.f=f;
  unsigned r=v.u+0x7fff+((v.u>>16)&1u);
  return (unsigned short)(r>>16);
}
__device__ __forceinline__ float b2f(unsigned short h){
  union{unsigned u;float f;} v; v.u=((unsigned)h)<<16; return v.f;
}
// fast transcendentals: v_exp_f32 + v_rcp_f32 (error ~1e-6, far below bf16 noise)
__device__ __forceinline__ float fsigm(float x){ return __builtin_amdgcn_rcpf(1.f+__expf(-x)); }
__device__ __forceinline__ float ftanh(float x){ return 1.f-2.f*__builtin_amdgcn_rcpf(__expf(2.f*x)+1.f); }

// async global->LDS, 16B per lane. LDS dest = wave-uniform base + lane*16.
__device__ __forceinline__ void gload16(const unsigned short* g, unsigned short* l){
  __builtin_amdgcn_global_load_lds((const __attribute__((address_space(1))) u32*)g,
                                   (__attribute__((address_space(3))) u32*)l,
                                   16,0,0);
}

// ---------- graph preprocessing ----------
__global__ __launch_bounds__(256) void k_init(float* deg,int* cnt,float* colsum,float* colsq){
  int i=blockIdx.x*256+threadIdx.x;
  if(i<NN){deg[i]=1.0f;cnt[i]=0;}
  if(i<256){colsum[i]=0.f;colsq[i]=0.f;}
}

__global__ __launch_bounds__(256) void k_deg(const int* __restrict__ ei,const float* __restrict__ ew,
                                             float* deg,int* cnt){
  int e=blockIdx.x*256+threadIdx.x;
  if(e<NE){int d=ei[NE+e];atomicAdd(&deg[d],ew[e]);atomicAdd(&cnt[d],1);}
}

__global__ __launch_bounds__(256) void k_dinv(const float* __restrict__ deg,float* dinv){
  int i=blockIdx.x*256+threadIdx.x;
  if(i<NN){float d=deg[i];dinv[i]=d>0.f?rsqrtf(d):0.f;}
}

__global__ __launch_bounds__(1024) void k_scan(const int* __restrict__ cnt,int* row_ptr,int* cursor){
  __shared__ int s[1024];
  __shared__ int carry;
  int tid=threadIdx.x;
  if(tid==0)carry=0;
  __syncthreads();
  for(int base=0;base<NN;base+=1024){
    int i=base+tid;
    int v=(i<NN)?cnt[i]:0;
    s[tid]=v;__syncthreads();
    for(int off=1;off<1024;off<<=1){
      int t=(tid>=off)?s[tid-off]:0;
      __syncthreads();
      s[tid]+=t;__syncthreads();
    }
    int excl=carry+s[tid]-v;
    if(i<NN){row_ptr[i]=excl;cursor[i]=excl;}
    __syncthreads();
    if(tid==1023)carry+=s[1023];
    __syncthreads();
  }
  if(tid==0)row_ptr[NN]=carry;
}

__global__ __launch_bounds__(256) void k_scatter(const int* __restrict__ ei,const float* __restrict__ ew,
    const float* __restrict__ dinv,int* cursor,int* csr_src,float* csr_w){
  int e=blockIdx.x*256+threadIdx.x;
  if(e<NE){
    int s=ei[e],d=ei[NE+e];
    float wv=dinv[s]*ew[e]*dinv[d];
    int p=atomicAdd(&cursor[d],1);
    csr_src[p]=s;csr_w[p]=wv;
  }
}

// ---------- weight / input prep ----------
__global__ __launch_bounds__(256) void k_wt(const float* __restrict__ W,unsigned short* __restrict__ Wt){
  int j=blockIdx.x,k=threadIdx.x;
  Wt[j*256+k]=f2b(W[k*256+j]);
}
__global__ __launch_bounds__(256) void k_f2b(const float* __restrict__ s,unsigned short* __restrict__ d,int n){
  int i=blockIdx.x*256+threadIdx.x;
  if(i<n)d[i]=f2b(s[i]);
}
__global__ __launch_bounds__(256) void k_cast(const float* __restrict__ s,unsigned short* __restrict__ d){
  long i=(long)blockIdx.x*256+threadIdx.x;   // one float4 -> ushort4 per thread
  float4 v=*(const float4*)&s[i*4];
  ushort4 o;o.x=f2b(v.x);o.y=f2b(v.y);o.z=f2b(v.z);o.w=f2b(v.w);
  *(ushort4*)&d[i*4]=o;
}
__global__ __launch_bounds__(256) void k_bsum(const float* __restrict__ a,const float* __restrict__ b,
                                              float* __restrict__ s,int n){
  int i=blockIdx.x*256+threadIdx.x;
  if(i<n)s[i]=a[i]+b[i];
}

// ---------- dense MFMA GEMM: Cb[M,256](bf16) = A[M,K](bf16) @ Bt^T (Bt is [256][K] bf16) ----------
// gload_lds-staged, double-buffered, 2-phase. LDS tile row pitch 32 (linear), chunk-XOR swizzle
// (chunk ^= (row>>1)&3) applied on the SOURCE address (write side) and on ds_read (read side).
__global__ __launch_bounds__(256,2) void k_gemm_mfma(
    const unsigned short* __restrict__ A,int lda,const unsigned short* __restrict__ Bt,int K,
    unsigned short* __restrict__ Cb){
  __shared__ unsigned short As[2][4096];   // 128 rows x 32 k
  __shared__ unsigned short Bs[2][4096];
  int tid=threadIdx.x;
  int row0=blockIdx.x*128,col0=blockIdx.y*128;
  int lane=tid&63,l15=lane&15,quad=lane>>4;
  int wid=tid>>6,wm=wid>>1,wn=wid&1;
  int sr=tid>>2;                           // staging row 0..63 (per 64-row half)
  int aoff=((tid&3)^((tid>>3)&3))*8;       // pre-swizzled source chunk offset (ushorts)
  int xq=quad^((l15>>1)&3);                // read-side physical chunk
  long ar0=row0+sr;    if(ar0>=NN)ar0=NN-1;   // clamp: garbage rows only feed skipped outputs
  long ar1=row0+64+sr; if(ar1>=NN)ar1=NN-1;
  const unsigned short* a0p=A+ar0*lda+aoff;
  const unsigned short* a1p=A+ar1*lda+aoff;
  const unsigned short* b0p=Bt+(long)(col0+sr)*K+aoff;
  const unsigned short* b1p=Bt+(long)(col0+64+sr)*K+aoff;
  int lb=wid*512;                          // wave-uniform LDS base (ushorts)
  f32x4 acc[4][4]={};
  int nt=K/32;
  gload16(a0p,&As[0][lb]); gload16(a1p,&As[0][2048+lb]);
  gload16(b0p,&Bs[0][lb]); gload16(b1p,&Bs[0][2048+lb]);
  __syncthreads();
  for(int t=0;t<nt;t++){
    int cur=t&1;
    if(t+1<nt){
      int k0=(t+1)*32;int nxt=cur^1;
      gload16(a0p+k0,&As[nxt][lb]); gload16(a1p+k0,&As[nxt][2048+lb]);
      gload16(b0p+k0,&Bs[nxt][lb]); gload16(b1p+k0,&Bs[nxt][2048+lb]);
    }
    bf8 af[4],bfg[4];
    #pragma unroll
    for(int i=0;i<4;i++){
      af[i] =*(const bf8*)&As[cur][(wm*64+i*16+l15)*32+xq*8];
      bfg[i]=*(const bf8*)&Bs[cur][(wn*64+i*16+l15)*32+xq*8];
    }
    #pragma unroll
    for(int mi=0;mi<4;mi++)
      #pragma unroll
      for(int ni=0;ni<4;ni++)
        acc[mi][ni]=__builtin_amdgcn_mfma_f32_16x16x32_bf16(af[mi],bfg[ni],acc[mi][ni],0,0,0);
    __syncthreads();
  }
  #pragma unroll
  for(int mi=0;mi<4;mi++){
    #pragma unroll
    for(int r=0;r<4;r++){
      int node=row0+wm*64+mi*16+quad*4+r;
      if(node>=NN)continue;
      #pragma unroll
      for(int ni=0;ni<4;ni++){
        int col=col0+wn*64+ni*16+l15;
        Cb[(long)node*256+col]=f2b(acc[mi][ni][r]);
      }
    }
  }
}

// ---------- fused 3-gate LSTM MFMA: h = sig(o)*tanh(sig(i)*tanh(g)) ----------
__global__ __launch_bounds__(256,2) void k_lstm_mfma(
    const unsigned short* __restrict__ A,int lda,int K,
    const unsigned short* __restrict__ Wb,const float* __restrict__ bsum,
    float* __restrict__ Hout,int ldh,unsigned short* __restrict__ Hb){
  __shared__ unsigned short As[2][4096];   // 128 rows x 32 k
  __shared__ unsigned short Bs[2][6144];   // 3 gates x 64 rows x 32 k
  int tid=threadIdx.x;
  int row0=blockIdx.x*128,m0=blockIdx.y*64;
  int lane=tid&63,l15=lane&15,quad=lane>>4;
  int wid=tid>>6,wm=wid>>1,wn=wid&1;
  int sr=tid>>2;
  int aoff=((tid&3)^((tid>>3)&3))*8;
  int xq=quad^((l15>>1)&3);
  long ar0=row0+sr;    if(ar0>=NN)ar0=NN-1;
  long ar1=row0+64+sr; if(ar1>=NN)ar1=NN-1;
  const unsigned short* a0p=A+ar0*lda+aoff;
  const unsigned short* a1p=A+ar1*lda+aoff;
  const unsigned short* wip=Wb+(long)(    m0+sr)*K+aoff;   // i gate
  const unsigned short* wgp=Wb+(long)(512+m0+sr)*K+aoff;   // g gate
  const unsigned short* wop=Wb+(long)(768+m0+sr)*K+aoff;   // o gate
  int lb=wid*512;
  f32x4 ai[4][2]={},ag[4][2]={},ao[4][2]={};
  int nt=K/32;
  gload16(a0p,&As[0][lb]); gload16(a1p,&As[0][2048+lb]);
  gload16(wip,&Bs[0][lb]); gload16(wgp,&Bs[0][2048+lb]); gload16(wop,&Bs[0][4096+lb]);
  __syncthreads();
  for(int t=0;t<nt;t++){
    int cur=t&1;
    if(t+1<nt){
      int k0=(t+1)*32;int nxt=cur^1;
      gload16(a0p+k0,&As[nxt][lb]); gload16(a1p+k0,&As[nxt][2048+lb]);
      gload16(wip+k0,&Bs[nxt][lb]); gload16(wgp+k0,&Bs[nxt][2048+lb]); gload16(wop+k0,&Bs[nxt][4096+lb]);
    }
    bf8 af[4],bi[2],bg[2],bo[2];
    #pragma unroll
    for(int i=0;i<4;i++)af[i]=*(const bf8*)&As[cur][(wm*64+i*16+l15)*32+xq*8];
    #pragma unroll
    for(int ni=0;ni<2;ni++){
      int rr=wn*32+ni*16+l15;
      bi[ni]=*(const bf8*)&Bs[cur][(    rr)*32+xq*8];
      bg[ni]=*(const bf8*)&Bs[cur][( 64+rr)*32+xq*8];
      bo[ni]=*(const bf8*)&Bs[cur][(128+rr)*32+xq*8];
    }
    #pragma unroll
    for(int mi=0;mi<4;mi++)
      #pragma unroll
      for(int ni=0;ni<2;ni++){
        ai[mi][ni]=__builtin_amdgcn_mfma_f32_16x16x32_bf16(af[mi],bi[ni],ai[mi][ni],0,0,0);
        ag[mi][ni]=__builtin_amdgcn_mfma_f32_16x16x32_bf16(af[mi],bg[ni],ag[mi][ni],0,0,0);
        ao[mi][ni]=__builtin_amdgcn_mfma_f32_16x16x32_bf16(af[mi],bo[ni],ao[mi][ni],0,0,0);
      }
    __syncthreads();
  }
  #pragma unroll
  for(int ni=0;ni<2;ni++){
    int m=m0+wn*32+ni*16+l15;
    float b_i=bsum[m],b_g=bsum[512+m],b_o=bsum[768+m];
    #pragma unroll
    for(int mi=0;mi<4;mi++){
      #pragma unroll
      for(int r=0;r<4;r++){
        int node=row0+wm*64+mi*16+quad*4+r;
        if(node>=NN)continue;
        float gi=ai[mi][ni][r]+b_i;
        float gg=ag[mi][ni][r]+b_g;
        float go=ao[mi][ni][r]+b_o;
        float c=fsigm(gi)*ftanh(gg);
        float h=fsigm(go)*ftanh(c);
        Hout[(long)node*ldh+m]=h;
        if(Hb)Hb[(long)node*256+m]=f2b(h);
      }
    }
  }
}

// ---------- SpMM (bf16 T) + self-loop + bias + ReLU + stats; wave-per-row, ILP-2 ----------
__global__ __launch_bounds__(256) void k_spmm(const unsigned short* __restrict__ Tb,
    const int* __restrict__ row_ptr,const int* __restrict__ csr_src,const float* __restrict__ csr_w,
    const float* __restrict__ dinv,const float* __restrict__ bias,
    unsigned short* __restrict__ Xb,float* colsum,float* colsq){
  __shared__ float s_sum[4][256];
  __shared__ float s_sq[4][256];
  int tid=threadIdx.x;
  int lane=tid&63,wv=tid>>6;
  int c4=lane*4;
  float4 bc=*(const float4*)&bias[c4];
  float sum0=0.f,sum1=0.f,sum2=0.f,sum3=0.f;
  float sq0=0.f,sq1=0.f,sq2=0.f,sq3=0.f;
  int rowbase=blockIdx.x*32+wv*8;
  #pragma unroll 1
  for(int pr=0;pr<4;pr++){
    int ra=rowbase+pr*2,rb=ra+1;
    bool va=ra<NN,vb=rb<NN;
    int raa=va?ra:0,rbb=vb?rb:0;
    int p0a=row_ptr[raa],p1a=row_ptr[raa+1];
    int p0b=row_ptr[rbb],p1b=row_ptr[rbb+1];
    int la=va?(p1a-p0a):0,lb=vb?(p1b-p0b):0;
    float dia=dinv[raa],dib=dinv[rbb];
    ushort4 tsa=*(const ushort4*)&Tb[(long)raa*256+c4];
    ushort4 tsb=*(const ushort4*)&Tb[(long)rbb*256+c4];
    float wsa=dia*dia,wsb=dib*dib;
    float a0=wsa*b2f(tsa.x),a1=wsa*b2f(tsa.y),a2=wsa*b2f(tsa.z),a3=wsa*b2f(tsa.w);
    float b0=wsb*b2f(tsb.x),b1=wsb*b2f(tsb.y),b2=wsb*b2f(tsb.z),b3=wsb*b2f(tsb.w);
    int L=max(la,lb);
    for(int j=0;j<L;j++){
      int ia=j<la?(p0a+j):p0a;
      int ib=j<lb?(p0b+j):p0b;
      float wa=j<la?csr_w[ia]:0.f;
      float wb=j<lb?csr_w[ib]:0.f;
      int sa=csr_src[ia];sa=min(max(sa,0),NN-1);
      int sb=csr_src[ib];sb=min(max(sb,0),NN-1);
      ushort4 ta=*(const ushort4*)&Tb[(long)sa*256+c4];
      ushort4 tb=*(const ushort4*)&Tb[(long)sb*256+c4];
      a0+=wa*b2f(ta.x);a1+=wa*b2f(ta.y);a2+=wa*b2f(ta.z);a3+=wa*b2f(ta.w);
      b0+=wb*b2f(tb.x);b1+=wb*b2f(tb.y);b2+=wb*b2f(tb.z);b3+=wb*b2f(tb.w);
    }
    if(va){
      a0=fmaxf(a0+bc.x,0.f);a1=fmaxf(a1+bc.y,0.f);a2=fmaxf(a2+bc.z,0.f);a3=fmaxf(a3+bc.w,0.f);
      ushort4 o;o.x=f2b(a0);o.y=f2b(a1);o.z=f2b(a2);o.w=f2b(a3);
      *(ushort4*)&Xb[(long)ra*512+c4]=o;
      sum0+=a0;sum1+=a1;sum2+=a2;sum3+=a3;
      sq0+=a0*a0;sq1+=a1*a1;sq2+=a2*a2;sq3+=a3*a3;
    }
    if(vb){
      b0=fmaxf(b0+bc.x,0.f);b1=fmaxf(b1+bc.y,0.f);b2=fmaxf(b2+bc.z,0.f);b3=fmaxf(b3+bc.w,0.f);
      ushort4 o;o.x=f2b(b0);o.y=f2b(b1);o.z=f2b(b2);o.w=f2b(b3);
      *(ushort4*)&Xb[(long)rb*512+c4]=o;
      sum0+=b0;sum1+=b1;sum2+=b2;sum3+=b3;
      sq0+=b0*b0;sq1+=b1*b1;sq2+=b2*b2;sq3+=b3*b3;
    }
  }
  s_sum[wv][c4+0]=sum0;s_sum[wv][c4+1]=sum1;s_sum[wv][c4+2]=sum2;s_sum[wv][c4+3]=sum3;
  s_sq[wv][c4+0]=sq0;s_sq[wv][c4+1]=sq1;s_sq[wv][c4+2]=sq2;s_sq[wv][c4+3]=sq3;
  __syncthreads();
  if(tid<256){
    float a=s_sum[0][tid]+s_sum[1][tid]+s_sum[2][tid]+s_sum[3][tid];
    float q=s_sq[0][tid]+s_sq[1][tid]+s_sq[2][tid]+s_sq[3][tid];
    atomicAdd(&colsum[tid],a);
    atomicAdd(&colsq[tid],q);
  }
}

__global__ __launch_bounds__(256) void k_bnfin(const float* __restrict__ gamma,const float* __restrict__ beta,
    float* colsum,float* colsq,float* scale,float* shift){
  int c=threadIdx.x;
  float mu=colsum[c]/(float)NN;
  float var=colsq[c]/(float)NN-mu*mu;
  float r=rsqrtf(var+1e-5f);
  float sc=r*gamma[c];
  scale[c]=sc;
  shift[c]=beta[c]-mu*sc;
  colsum[c]=0.f;colsq[c]=0.f;
}

__global__ __launch_bounds__(256) void k_bnapply(unsigned short* __restrict__ Xb,
    const float* __restrict__ scale,const float* __restrict__ shift){
  long idx=(long)blockIdx.x*256+threadIdx.x;
  long r=idx>>6;int c=(int)(idx&63)*4;
  if(r<NN){
    ushort4 v=*(const ushort4*)&Xb[r*512+c];
    ushort4 w;
    w.x=f2b(b2f(v.x)*scale[c+0]+shift[c+0]);
    w.y=f2b(b2f(v.y)*scale[c+1]+shift[c+1]);
    w.z=f2b(b2f(v.z)*scale[c+2]+shift[c+2]);
    w.w=f2b(b2f(v.w)*scale[c+3]+shift[c+3]);
    *(ushort4*)&Xb[r*512+c]=w;
  }
}

__global__ __launch_bounds__(256) void k_copy_out(const float* __restrict__ src,
    float* __restrict__ out,int colofs){
  long idx=(long)blockIdx.x*256+threadIdx.x;
  long r=idx>>6;int cc=(int)(idx&63)*4;
  if(r<NN)*(float4*)&out[r*768+colofs+cc]=*(const float4*)&src[r*256+cc];
}

extern "C" void kernel_launch(void* const* d_in,const int* in_sizes,int n_in,
                              void* d_out,int out_size,void* d_ws,size_t ws_size,
                              hipStream_t stream){
  const float* x   =(const float*)d_in[0];
  const int*   ei  =(const int*)  d_in[1];
  const float* ew  =(const float*)d_in[2];
  const float* W1  =(const float*)d_in[3];
  const float* b1  =(const float*)d_in[4];
  const float* W2  =(const float*)d_in[5];
  const float* b2  =(const float*)d_in[6];
  const float* g1  =(const float*)d_in[7];
  const float* be1 =(const float*)d_in[8];
  const float* g2  =(const float*)d_in[9];
  const float* be2 =(const float*)d_in[10];
  const float* Wih1=(const float*)d_in[11];
  const float* bih1=(const float*)d_in[13];
  const float* bhh1=(const float*)d_in[14];
  const float* Wih2=(const float*)d_in[15];
  const float* bih2=(const float*)d_in[17];
  const float* bhh2=(const float*)d_in[18];
  float* out=(float*)d_out;

  char* w=(char*)d_ws;
  auto alloc=[&](size_t bytes)->char*{char* p=w;w+=(bytes+255)&~(size_t)255;return p;};
  float* deg    =(float*)alloc((size_t)NN*4);
  float* dinv   =(float*)alloc((size_t)NN*4);
  int*   cnt    =(int*)  alloc((size_t)NN*4);
  int*   row_ptr=(int*)  alloc((size_t)(NN+1)*4);
  int*   cursor =(int*)  alloc((size_t)NN*4);
  int*   csr_src=(int*)  alloc((size_t)NE*4);
  float* csr_w  =(float*)alloc((size_t)NE*4);
  float* colsum =(float*)alloc(256*4);
  float* colsq  =(float*)alloc(256*4);
  float* scale  =(float*)alloc(256*4);
  float* shift  =(float*)alloc(256*4);
  unsigned short* Xcb =(unsigned short*)alloc((size_t)NN*512*2);  // [h1n|h2n] bf16, ld 512
  unsigned short* TbH =(unsigned short*)alloc((size_t)NN*256*2);  // GEMM out / LSTM1 hidden (aliased)
  unsigned short* xb  =(unsigned short*)alloc((size_t)NN*256*2);  // x cast to bf16
  unsigned short* Wt1 =(unsigned short*)alloc(256*256*2);
  unsigned short* Wt2 =(unsigned short*)alloc(256*256*2);
  unsigned short* Wb1 =(unsigned short*)alloc((size_t)1024*512*2);
  unsigned short* Wb2 =(unsigned short*)alloc((size_t)1024*256*2);
  float* bs1 =(float*)alloc(1024*4);
  float* bs2 =(float*)alloc(1024*4);

  int nb=(NN+255)/256;
  k_init<<<nb,256,0,stream>>>(deg,cnt,colsum,colsq);
  k_deg<<<(NE+255)/256,256,0,stream>>>(ei,ew,deg,cnt);
  k_dinv<<<nb,256,0,stream>>>(deg,dinv);
  k_scan<<<1,1024,0,stream>>>(cnt,row_ptr,cursor);
  k_scatter<<<(NE+255)/256,256,0,stream>>>(ei,ew,dinv,cursor,csr_src,csr_w);

  k_wt<<<256,256,0,stream>>>(W1,Wt1);
  k_wt<<<256,256,0,stream>>>(W2,Wt2);
  k_cast<<<12500,256,0,stream>>>(x,xb);      // 50000*256/4 threads exactly
  k_f2b<<<(1024*512+255)/256,256,0,stream>>>(Wih1,Wb1,1024*512);
  k_f2b<<<(1024*256+255)/256,256,0,stream>>>(Wih2,Wb2,1024*256);
  k_bsum<<<4,256,0,stream>>>(bih1,bhh1,bs1,1024);
  k_bsum<<<4,256,0,stream>>>(bih2,bhh2,bs2,1024);

  int ngx=(NN+127)/128;
  dim3 gd(ngx,2);   // dense GEMM: 256 cols / 128
  dim3 gl(ngx,4);   // lstm: 256 h-cols / 64
  int nspmm=(NN+31)/32;

  // layer 1
  k_gemm_mfma<<<gd,256,0,stream>>>(xb,256,Wt1,256,TbH);
  k_spmm<<<nspmm,256,0,stream>>>(TbH,row_ptr,csr_src,csr_w,dinv,b1,Xcb+0,colsum,colsq);
  k_bnfin<<<1,256,0,stream>>>(g1,be1,colsum,colsq,scale,shift);
  k_bnapply<<<12500,256,0,stream>>>(Xcb+0,scale,shift);
  // layer 2
  k_gemm_mfma<<<gd,256,0,stream>>>(Xcb,512,Wt2,256,TbH);
  k_spmm<<<nspmm,256,0,stream>>>(TbH,row_ptr,csr_src,csr_w,dinv,b2,Xcb+256,colsum,colsq);
  k_bnfin<<<1,256,0,stream>>>(g2,be2,colsum,colsq,scale,shift);
  k_bnapply<<<12500,256,0,stream>>>(Xcb+256,scale,shift);
  // LSTM1: A=Xcb [N,512] -> out[0:256) fp32 + TbH bf16 (TbH dead after spmm2)
  k_lstm_mfma<<<gl,256,0,stream>>>(Xcb,512,512,Wb1,bs1,out+0,768,TbH);
  // LSTM2: A=TbH [N,256] -> out[256:512)
  k_lstm_mfma<<<gl,256,0,stream>>>(TbH,256,256,Wb2,bs2,out+256,768,nullptr);
  // x passthrough
  k_copy_out<<<12500,256,0,stream>>>(x,out,512);
}